// Round 11
// baseline (329.332 us; speedup 1.0000x reference)
//
#include <hip/hip_runtime.h>

typedef unsigned short u16;
typedef unsigned long long u64;
typedef __attribute__((ext_vector_type(8))) short short8;
typedef __attribute__((ext_vector_type(4))) float f32x4;

#define MFMA16(a,b,c) __builtin_amdgcn_mfma_f32_16x16x32_bf16(a,b,c,0,0,0)

// ---- problem constants ----
#define B_SZ   32768
#define NNODE  64
#define NB_PAIR (B_SZ*NNODE)           // 2097152
#define OUT_PROJ   327680
#define OUT_ENT    458752
#define OUT_ORTHO  458753

// ---- workspace byte offsets ----
#define OFF_SCAL   ((size_t)0)                          // float[128]; [127] = isfp32
#define OFF_ADJ    ((size_t)512)                        // u16[4096] adjb
#define OFF_BEFF   (OFF_ADJ  + 8192u)                   // float[1024]
#define OFF_WEFF   (OFF_BEFF + 4096u)                   // u16[1024*64]
#define OFF_WCAT   (OFF_WEFF + 131072u)                 // u16[32*1024] (K-permuted)
#define OFF_S1     (OFF_WCAT + 65536u)                  // float[1024*3]
#define OFF_S2     (OFF_S1   + 12288u)                  // float[1024*3]
#define OFF_S3     (OFF_S2   + 12288u)                  // float[1024*192] (32-row blocks)
#define OFF_S4     (OFF_S3   + 2048u*192u*4u)           // float[256*2]
#define OFF_H      (OFF_S4   + 8192u)                   // float[32768*8]
#define OFF_W01    (OFF_H    + (size_t)B_SZ*8u*4u)      // u32[NB_PAIR] packed (w0|gate)
#define OFF_CAN    (OFF_W01  + (size_t)NB_PAIR*4u)      // canonical bf16 inputs

#define CAN_X      0u
#define CAN_WEMB   2097152u
#define CAN_WREAD  (CAN_WEMB + 65536u)
#define CAN_SCW1   (CAN_WREAD + 10240u)
#define CAN_SMALL  (CAN_SCW1 + 8192u)
#define CAN_TOTAL  (CAN_SMALL + 11008u)
#define OFF_BEX    (((OFF_CAN + (size_t)CAN_TOTAL*2u) + 63u) & ~(size_t)63u)
#define OFF_WET    (OFF_BEX + 48u*16u*2u)               // u16[1024*64] wembT
#define OFF_VW     (OFF_WET + 131072u)                  // u16[1024*64] Vw
#define OFF_VB     (OFF_VW  + 131072u)                  // float[1024] vbias
#define OFF_WC     (OFF_VB  + 4096u)                    // u16[1024*64] Wc
#define OFF_SW     (OFF_WC  + 131072u)                  // u16[192*64] Sw
#define OFF_BC2    (OFF_SW  + 24576u)                   // float[1024] bc
#define OFF_SB     (OFF_BC2 + 4096u)                    // float[192] sb
#define OFF_DR     (OFF_SB  + 1024u)                    // double[192] dred (unused, kept for layout)
#define WS_NEEDED  (OFF_DR  + 192u*8u)

__device__ __forceinline__ float bf2f(u16 u){
    unsigned v = ((unsigned)u) << 16;
    return __builtin_bit_cast(float, v);
}
__device__ __forceinline__ u16 f2bf(float f){
    unsigned u = __builtin_bit_cast(unsigned, f);
    u += 0x7FFFu + ((u >> 16) & 1u);           // RTN-even
    return (u16)(u >> 16);
}
__device__ __forceinline__ float sigm(float x){ return 1.f/(1.f + expf(-x)); }
__device__ __forceinline__ u16 conv_one(const void* src, int i, int isfp32){
    return isfp32 ? f2bf(((const float*)src)[i]) : ((const u16*)src)[i];
}
__device__ __forceinline__ void store_out(void* dout, int idx, float v, int isfp32){
    if (isfp32) ((float*)dout)[idx] = v;
    else        ((u16*)dout)[idx]   = f2bf(v);
}
__device__ __forceinline__ double blk_red(double v, double* sred, int tid){
    #pragma unroll
    for (int off = 32; off > 0; off >>= 1) v += __shfl_xor(v, off);
    if ((tid & 63) == 0) sred[tid >> 6] = v;
    __syncthreads();
    double r = sred[0] + sred[1] + sred[2] + sred[3];
    __syncthreads();
    return r;
}
// 4 independent block reductions sharing ONE barrier.
__device__ __forceinline__ void blk_red4(double* v, double* sred, int tid){
    #pragma unroll
    for (int off = 32; off > 0; off >>= 1){
        v[0] += __shfl_xor(v[0], off);
        v[1] += __shfl_xor(v[1], off);
        v[2] += __shfl_xor(v[2], off);
        v[3] += __shfl_xor(v[3], off);
    }
    if ((tid & 63) == 0){
        int w = tid >> 6;
        sred[w*4+0] = v[0]; sred[w*4+1] = v[1];
        sred[w*4+2] = v[2]; sred[w*4+3] = v[3];
    }
    __syncthreads();
    #pragma unroll
    for (int k = 0; k < 4; ++k)
        v[k] = sred[0*4+k] + sred[1*4+k] + sred[2*4+k] + sred[3*4+k];
    __syncthreads();
}

__device__ void run_regulator(const u16* w1, const u16* b1, const u16* g,
                              const u16* be, const u16* w2, const u16* b2,
                              const float* sig, int in_dim, float* out)
{
    float h[16];
    float mu = 0.f;
    for (int i = 0; i < 16; ++i){
        float a = bf2f(b1[i]);
        for (int j = 0; j < in_dim; ++j) a += sig[j]*bf2f(w1[i*in_dim + j]);
        h[i] = a; mu += a;
    }
    mu *= 0.0625f;
    float var = 0.f;
    for (int i = 0; i < 16; ++i){ float d = h[i]-mu; var += d*d; }
    var *= 0.0625f;
    float inv = 1.f / sqrtf(var + 1e-5f);
    for (int i = 0; i < 16; ++i){
        float hn = (h[i]-mu)*inv;
        h[i] = tanhf(hn*bf2f(g[i]) + bf2f(be[i]));
    }
    for (int c = 0; c < 3; ++c){
        float o = bf2f(b2[c]);
        for (int i = 0; i < 16; ++i) o += h[i]*bf2f(w2[c*16 + i]);
        out[c] = sigm(o);
    }
}

// per-block dtype probe (reads first 4KB of x, block-level reduction)
__device__ __forceinline__ int probe_isfp32(const u16* xraw, int tid, int* sred)
{
    int c = 0;
    #pragma unroll
    for (int j = 0; j < 4; ++j){
        u16 u = xraw[(tid*4 + j)*2];
        int e = (u >> 7) & 0xFF;
        if (u == 0 || (e >= 90 && e <= 140)) c++;
    }
    #pragma unroll
    for (int off = 32; off > 0; off >>= 1) c += __shfl_xor(c, off);
    if ((tid & 63) == 0) sred[tid >> 6] = c;
    __syncthreads();
    int tot = sred[0]+sred[1]+sred[2]+sred[3];
    __syncthreads();
    return tot < 614;
}

// vectorized big-copy: bf16 -> short8 passthrough; fp32 -> float4x2 + pack.
// nvec = count/8; identical values to conv_one per element.
__device__ __forceinline__ void copy_big(const void* src, u16* dst, int nvec,
                                         int gid, int stride, int isfp32)
{
    if (!isfp32){
        const short8* s = (const short8*)src;
        for (int i = gid; i < nvec; i += stride) *(short8*)(dst + i*8) = s[i];
    } else {
        const f32x4* s = (const f32x4*)src;
        for (int i = gid; i < nvec; i += stride){
            f32x4 v0 = s[i*2], v1 = s[i*2+1];
            u64 lo = (u64)f2bf(v0[0]) | ((u64)f2bf(v0[1])<<16) |
                     ((u64)f2bf(v0[2])<<32) | ((u64)f2bf(v0[3])<<48);
            u64 hi = (u64)f2bf(v1[0]) | ((u64)f2bf(v1[1])<<16) |
                     ((u64)f2bf(v1[2])<<32) | ((u64)f2bf(v1[3])<<48);
            *(u64*)(dst + i*8)     = lo;
            *(u64*)(dst + i*8 + 4) = hi;
        }
    }
}

// KC_ALL: single fused canonicalization launch (1425 blocks).
struct SmallTab { const void* src[36]; int cnt[36]; int off[36]; };
__global__ __launch_bounds__(256) void kc_all(SmallTab t,
    const void* x, const void* wemb, const void* wread_raw, const void* scw1_raw,
    const void* vslow_raw, const void* gatew_raw,
    u16* can, float* scal, u16* wcat, u16* wembT, u16* bex)
{
    __shared__ int sred[4];
    int b = blockIdx.x, tid = threadIdx.x;
    int isfp32 = probe_isfp32((const u16*)x, tid, sred);
    if (b == 0 && tid == 0) scal[127] = isfp32 ? 1.0f : 0.0f;
    if (b < 1024){
        int gid = b*256 + tid, stride = 1024*256;
        copy_big(x,         can + CAN_X,     262144, gid, stride, isfp32);
        copy_big(wemb,      can + CAN_WEMB,  8192,   gid, stride, isfp32);
        copy_big(wread_raw, can + CAN_WREAD, 1280,   gid, stride, isfp32);
        copy_big(scw1_raw,  can + CAN_SCW1,  1024,   gid, stride, isfp32);
    } else if (b < 1040){
        int gid = (b-1024)*256 + tid, stride = 16*256;
        for (int e = 0; e < 36; ++e){
            const void* s = t.src[e];
            u16* d = can + t.off[e];
            int n = t.cnt[e];
            for (int i = gid; i < n; i += stride) d[i] = conv_one(s, i, isfp32);
        }
    } else if (b < 1168){
        int idx = (b-1040)*256 + tid;
        int row = idx >> 10, k = idx & 1023;
        u16 v = 0;
        if (row < 10)      v = conv_one(wread_raw, row*1024 + k, isfp32);
        else if (row < 18) v = conv_one(scw1_raw, (row-10)*1024 + k, isfp32);
        int lo = k & 31;
        int khw = ((lo >> 2) & 3)*8 + ((lo >> 4) << 2) + (lo & 3);
        wcat[row*1024 + (k & ~31) + khw] = v;
    } else if (b < 1424){
        int idx = (b-1168)*256 + tid;
        int m = idx >> 10, jj = idx & 1023;
        wembT[jj*64 + m] = conv_one(wemb, m*1024 + jj, isfp32);
    } else {
        if (tid < 16){
            float a = 0.f;
            for (int i = 0; i < 16; ++i)
                a += bf2f(conv_one(gatew_raw, i, isfp32))*bf2f(conv_one(vslow_raw, i*16+tid, isfp32));
            bex[32*16+tid] = f2bf(a);
        }
    }
}

// K1 v2 (B-in-regs, wide): grid 1024 = 16 colgroups x 64 rowchunks.
__global__ __launch_bounds__(256) void k1_embed(const u16* x, const u16* wemb,
                                                const u16* bemb, float* s1)
{
    __shared__ float red[12];
    int tid = threadIdx.x, wave = tid>>6, lane = tid&63;
    int m = lane&15, quad = lane>>4;
    int cg = blockIdx.x & 15, rc = blockIdx.x >> 4;
    short8 b0[4], b1[4];
    float bias[4];
    #pragma unroll
    for (int s = 0; s < 4; ++s){
        int col = cg*64 + s*16 + m;
        b0[s] = *(const short8*)(wemb + col*64 + quad*8);
        b1[s] = *(const short8*)(wemb + col*64 + quad*8 + 32);
        bias[s] = bf2f(bemb[col]);
    }
    float sx = 0.f, sxx = 0.f, sabs = 0.f;
    const u16* xbase = x + (size_t)(rc*512 + wave*128 + m)*64 + quad*8;
    #pragma unroll 4
    for (int it = 0; it < 8; ++it){
        const u16* xr = xbase + (size_t)it*16*64;
        short8 a0 = *(const short8*)xr;
        short8 a1 = *(const short8*)(xr + 32);
        if (cg == 0){
            #pragma unroll
            for (int j = 0; j < 8; ++j){
                float f0 = bf2f((u16)a0[j]); sx += f0; sxx += f0*f0;
                float f1 = bf2f((u16)a1[j]); sx += f1; sxx += f1*f1;
            }
        }
        #pragma unroll
        for (int s = 0; s < 4; ++s){
            f32x4 zc = {0.f,0.f,0.f,0.f};
            f32x4 c = MFMA16(a0, b0[s], zc);
            c = MFMA16(a1, b1[s], c);
            #pragma unroll
            for (int r = 0; r < 4; ++r)
                sabs += fabsf(c[r]+bias[s]);
        }
    }
    #pragma unroll
    for (int off = 32; off > 0; off >>= 1){
        sx   += __shfl_xor(sx, off);
        sxx  += __shfl_xor(sxx, off);
        sabs += __shfl_xor(sabs, off);
    }
    if (lane == 0){ red[wave*3] = sx; red[wave*3+1] = sxx; red[wave*3+2] = sabs; }
    __syncthreads();
    if (tid == 0){
        for (int k = 0; k < 3; ++k)
            s1[blockIdx.x*3 + k] = red[k] + red[3+k] + red[6+k] + red[9+k];
    }
}

// K2: pr regulator -> pl0; build adjb + beff (single-barrier 4-way reduction)
__global__ __launch_bounds__(256) void k2_adj(const u16* adjw, const u16* adjm, const u16* bemb,
    const u16* w1, const u16* b1, const u16* g, const u16* be, const u16* w2, const u16* b2,
    const float* s1, float* scal, u16* adjb, float* beff)
{
    __shared__ double sred[16];
    __shared__ float raw[4096];
    __shared__ float rowsum[64];
    __shared__ float bembs[1024];
    __shared__ float pl0s;
    int tid = threadIdx.x;
    for (int i = tid; i < 1024; i += 256) bembs[i] = bf2f(bemb[i]);
    double v[4] = {0,0,0,0};
    for (int i = tid; i < 1024; i += 256){
        v[0] += (double)s1[i*3]; v[1] += (double)s1[i*3+1]; v[2] += (double)s1[i*3+2];
    }
    for (int i = tid; i < 4096; i += 256){ float f = bf2f(adjw[i]); v[3] += (double)(f*f); }
    blk_red4(v, sred, tid);
    if (tid == 0){
        double nx = 2097152.0;
        float sg[3];
        sg[0] = (float)((v[1] - v[0]*v[0]/nx)/(nx - 1.0));
        sg[1] = (float)(v[2] / 33554432.0);
        sg[2] = sqrtf((float)v[3]);
        float o[3];
        run_regulator(w1,b1,g,be,w2,b2, sg, 3, o);
        scal[0] = o[0]; pl0s = o[0];
    }
    __syncthreads();
    float pl0 = pl0s;
    for (int i = tid; i < 4096; i += 256)
        raw[i] = sigm(bf2f(adjw[i])*pl0) * bf2f(adjm[i]);
    __syncthreads();
    if (tid < 64){
        float r = 0.f;
        for (int mc = 0; mc < 64; ++mc) r += raw[tid*64 + mc];
        rowsum[tid] = fmaxf(r, 1e-6f);
    }
    __syncthreads();
    for (int i = tid; i < 4096; i += 256) adjb[i] = f2bf(raw[i] / rowsum[i>>6]);
    for (int o = tid; o < 1024; o += 256){
        int n = o >> 4, d = o & 15;
        float a = 0.f;
        for (int m = 0; m < 64; ++m) a += raw[n*64+m]*bembs[m*16+d];
        beff[o] = a / rowsum[n];
    }
}

// K2b (MFMA): Weff = adjb @ Wr
__global__ __launch_bounds__(256) void k2b_mfma(const u16* adjb, const u16* wembT, u16* weff)
{
    int tid = threadIdx.x, wave = tid>>6, lane = tid&63;
    int m = lane&15, quad = lane>>4;
    const u16* ar = adjb + (wave*16 + m)*64 + quad*8;
    short8 a0 = *(const short8*)ar;
    short8 a1 = *(const short8*)(ar + 32);
    int col = blockIdx.x*16 + m;
    const u16* br = wembT + col*64 + quad*8;
    short8 b0 = *(const short8*)br;
    short8 b1 = *(const short8*)(br + 32);
    f32x4 acc = {0.f,0.f,0.f,0.f};
    acc = MFMA16(a0, b0, acc);
    acc = MFMA16(a1, b1, acc);
    #pragma unroll
    for (int r = 0; r < 4; ++r)
        weff[(size_t)(wave*16 + quad*4 + r)*1024 + blockIdx.x*16 + m] = f2bf(acc[r]);
}

// KVW: Vw = V@Weff (per node), vbias = V@beff
__global__ __launch_bounds__(256) void kvw(const u16* vslow, const u16* weff, const float* beff,
                                           u16* vw, float* vbias)
{
    __shared__ float Vs[256];
    int tid = threadIdx.x, b = blockIdx.x;
    Vs[tid] = bf2f(vslow[tid]);
    __syncthreads();
    if (b < 256){
        int idx = b*256 + tid;
        int j = idx >> 6, kf = idx & 63;
        int n = j >> 4, i = j & 15;
        float a = 0.f;
        #pragma unroll
        for (int d = 0; d < 16; ++d) a += Vs[i*16+d]*bf2f(weff[(size_t)(n*16+d)*64 + kf]);
        vw[(size_t)j*64 + kf] = f2bf(a);
    } else {
        int o = (b-256)*256 + tid;
        int n = o >> 4, i = o & 15;
        float a = 0.f;
        #pragma unroll
        for (int d = 0; d < 16; ++d) a += Vs[i*16+d]*beff[n*16+d];
        vbias[o] = a;
    }
}

// K3 v2 (B-in-regs, wide): grid 1024 = 16 colgroups x 64 rowchunks.
__global__ __launch_bounds__(256) void k3_stats(const u16* x, const u16* weff, const float* beff,
                                                const u16* vw, const float* vbias, float* s2)
{
    __shared__ float red[12];
    int tid = threadIdx.x, wave = tid>>6, lane = tid&63;
    int m = lane&15, quad = lane>>4;
    int cg = blockIdx.x & 15, rc = blockIdx.x >> 4;
    short8 wb0[4], wb1[4], vb0[4], vb1[4];
    float bev[4], vbv[4];
    #pragma unroll
    for (int s = 0; s < 4; ++s){
        int col = cg*64 + s*16 + m;
        wb0[s] = *(const short8*)(weff + (size_t)col*64 + quad*8);
        wb1[s] = *(const short8*)(weff + (size_t)col*64 + quad*8 + 32);
        vb0[s] = *(const short8*)(vw + (size_t)col*64 + quad*8);
        vb1[s] = *(const short8*)(vw + (size_t)col*64 + quad*8 + 32);
        bev[s] = beff[col];
        vbv[s] = vbias[col];
    }
    float psum=0.f, pssq=0.f, pabsv=0.f;
    const u16* xbase = x + (size_t)(rc*512 + wave*128 + m)*64 + quad*8;
    #pragma unroll 4
    for (int it = 0; it < 8; ++it){
        const u16* xr = xbase + (size_t)it*16*64;
        short8 a0 = *(const short8*)xr;
        short8 a1 = *(const short8*)(xr + 32);
        #pragma unroll
        for (int s = 0; s < 4; ++s){
            f32x4 zc = {0.f,0.f,0.f,0.f};
            f32x4 c = MFMA16(a0, wb0[s], zc);
            c = MFMA16(a1, wb1[s], c);
            f32x4 w = MFMA16(a0, vb0[s], zc);
            w = MFMA16(a1, vb1[s], w);
            #pragma unroll
            for (int r = 0; r < 4; ++r){
                float f0 = c[r] + bev[s];
                psum += f0; pssq += f0*f0;
                pabsv += fabsf(w[r] + vbv[s]);
            }
        }
    }
    #pragma unroll
    for (int off = 32; off > 0; off >>= 1){
        psum  += __shfl_xor(psum, off);
        pssq  += __shfl_xor(pssq, off);
        pabsv += __shfl_xor(pabsv, off);
    }
    if (lane == 0){ red[wave*3] = psum; red[wave*3+1] = pssq; red[wave*3+2] = pabsv; }
    __syncthreads();
    if (tid == 0){
        for (int k = 0; k < 3; ++k)
            s2[blockIdx.x*3 + k] = red[k] + red[3+k] + red[6+k] + red[9+k];
    }
}

// K3b: ctrl regulator + build bex dynamic rows (single-barrier 4-way reduction)
__global__ __launch_bounds__(256) void k3b_ctrl(const u16* wslow,
    const u16* vslow, const u16* wfast, const u16* wq, const u16* basis,
    const u16* w1, const u16* b1, const u16* g, const u16* be, const u16* w2, const u16* b2,
    const float* s2, float* scal, u16* bex)
{
    __shared__ double sred[16];
    __shared__ float ctrl2s;
    int tid = threadIdx.x;
    double v[4] = {0,0,0,0};
    for (int i = tid; i < 1024; i += 256){
        v[0] += (double)s2[i*3]; v[1] += (double)s2[i*3+1]; v[2] += (double)s2[i*3+2];
    }
    float wf = bf2f(wslow[tid]);
    v[3] = (double)(wf*wf);
    blk_red4(v, sred, tid);
    if (tid == 0){
        double M = 33554432.0;
        float sg[3];
        sg[0] = (float)((v[1] - v[0]*v[0]/M)/(M - 1.0));
        sg[1] = (float)(v[2] / M);
        sg[2] = sqrtf((float)v[3]);
        float o[3];
        run_regulator(w1,b1,g,be,w2,b2, sg, 3, o);
        scal[1] = o[0]; scal[2] = o[2];
        ctrl2s = o[2];
    }
    __syncthreads();
    float ctrl2 = ctrl2s;
    if (tid < 64){
        #pragma unroll
        for (int j = 0; j < 4; ++j){
            int idx = tid*4 + j;
            int d = idx >> 4, k = idx & 15;
            bex[(16+d)*16+k] = f2bf(bf2f(vslow[idx]) + ctrl2*bf2f(wfast[idx]));
        }
    } else if (tid < 96){
        int a = (tid-64) >> 4, k = (tid-64) & 15;
        float e = 0.f;
        for (int d = 0; d < 16; ++d){
            float bq = 0.f;
            for (int j = 0; j < 16; ++j) bq += bf2f(basis[a*16+j])*bf2f(wq[j*16+d]);
            e += bq*(bf2f(vslow[d*16+k]) + ctrl2*bf2f(wfast[d*16+k]));
        }
        bex[(33+a)*16+k] = f2bf(0.25f*e);
    }
}

// KBW: build Wc[(n,d)][64], Sw[(n,j)][64], bc[1024], sb[192]
__global__ __launch_bounds__(256) void kbw(const u16* bex, const u16* weff, const float* beff,
                                           const u16* gateb, u16* wc, u16* sw,
                                           float* bc, float* sb)
{
    __shared__ float BcL[256], gvL[16], e0L[16], e1L[16];
    int tid = threadIdx.x;
    if (tid < 256) BcL[tid] = bf2f(bex[(16 + (tid>>4))*16 + (tid&15)]);
    if (tid < 16){
        gvL[tid] = bf2f(bex[32*16+tid]);
        e0L[tid] = bf2f(bex[33*16+tid]);
        e1L[tid] = bf2f(bex[34*16+tid]);
    }
    __syncthreads();
    int id = blockIdx.x*256 + tid;
    if (id < 65536){
        int col = id >> 6, k = id & 63;
        int n = col >> 4, d = col & 15;
        float a = 0.f;
        #pragma unroll
        for (int dd = 0; dd < 16; ++dd)
            a += BcL[d*16+dd]*bf2f(weff[(size_t)(n*16+dd)*64 + k]);
        wc[(size_t)col*64 + k] = f2bf(a);
    } else if (id < 77824){
        int j2 = id - 65536;
        int scol = j2 >> 6, k = j2 & 63;
        int n = scol/3, j = scol - n*3;
        const float* sr = (j==0) ? gvL : (j==1) ? e0L : e1L;
        float a = 0.f;
        #pragma unroll
        for (int dd = 0; dd < 16; ++dd)
            a += sr[dd]*bf2f(weff[(size_t)(n*16+dd)*64 + k]);
        sw[(size_t)scol*64 + k] = f2bf(a);
    } else if (id < 78848){
        int col = id - 77824;
        int n = col >> 4, d = col & 15;
        float a = 0.f;
        #pragma unroll
        for (int dd = 0; dd < 16; ++dd) a += BcL[d*16+dd]*beff[n*16+dd];
        bc[col] = a;
    } else if (id < 79040){
        int s = id - 78848;
        int n = s/3, j = s - n*3;
        const float* sr = (j==0) ? gvL : (j==1) ? e0L : e1L;
        float a = 0.f;
        #pragma unroll
        for (int dd = 0; dd < 16; ++dd) a += sr[dd]*beff[n*16+dd];
        if (j == 0) a += bf2f(gateb[0]);
        sb[s] = a;
    }
}

// K4_stats v2: TWO 16-row streams per block (32 rows), sharing all sw/wc
// fragment loads. gt pitch 65 (conflict-free). 1024 blocks x 256 thr.
#define SCP 193
#define GTP 65
__global__ __launch_bounds__(256) void k4_stats(const u16* x, const u16* wc, const u16* sw,
    const float* bc, const float* sb, const float* scal, unsigned* wpack, float* s3)
{
    __shared__ float sc[32*SCP];
    __shared__ float gt[32*GTP];
    __shared__ float entp[256];
    __shared__ float snode[128];
    int tid = threadIdx.x, wave = tid>>6, lane = tid&63;
    int m = lane&15, quad = lane>>4;
    int row0 = blockIdx.x*32;
    const u16* xrA = x + (size_t)(row0 + m)*64 + quad*8;
    short8 a0A = *(const short8*)xrA;
    short8 a1A = *(const short8*)(xrA + 32);
    const u16* xrB = xrA + 16*64;
    short8 a0B = *(const short8*)xrB;
    short8 a1B = *(const short8*)(xrB + 32);
    float ctrl0 = scal[1];
    #pragma unroll
    for (int tt = 0; tt < 3; ++tt){
        int ct = wave*3 + tt;
        int scol = ct*16 + m;
        const u16* br = sw + (size_t)scol*64 + quad*8;
        short8 b0 = *(const short8*)br;
        short8 b1 = *(const short8*)(br + 32);
        f32x4 zc = {0.f,0.f,0.f,0.f};
        f32x4 cA = MFMA16(a0A, b0, zc);
        cA = MFMA16(a1A, b1, cA);
        f32x4 cB = MFMA16(a0B, b0, zc);
        cB = MFMA16(a1B, b1, cB);
        float sbv = sb[scol];
        #pragma unroll
        for (int r = 0; r < 4; ++r){
            sc[(quad*4+r)*SCP + scol]      = cA[r] + sbv;
            sc[(16+quad*4+r)*SCP + scol]   = cB[r] + sbv;
        }
    }
    __syncthreads();
    {
        int n = tid & 63, rgrp = tid >> 6;
        float ent = 0.f;
        #pragma unroll
        for (int rr = 0; rr < 8; ++rr){
            int row = rgrp*8 + rr;
            float gd  = sc[row*SCP + 3*n];
            float e0d = sc[row*SCP + 3*n + 1];
            float e1d = sc[row*SCP + 3*n + 2];
            float gate = ctrl0 / (1.f + __expf(-gd));
            float l0 = gate*e0d, l1 = gate*e1d;
            float w1v = 1.f/(1.f + __expf(l0 - l1));
            float w0v = 1.f - w1v;
            ent += -(w0v*__logf(w0v + 1e-8f) + w1v*__logf(w1v + 1e-8f));
            gt[row*GTP + n] = gate;
            wpack[(size_t)(row0 + row)*64 + n] =
                ((unsigned)f2bf(w0v) << 16) | (unsigned)f2bf(gate);
        }
        entp[tid] = ent;
    }
    __syncthreads();
    #pragma unroll
    for (int tt = 0; tt < 16; ++tt){
        int n = wave*16 + tt;
        int col = n*16 + m;
        const u16* br = wc + (size_t)col*64 + quad*8;
        short8 b0 = *(const short8*)br;
        short8 b1 = *(const short8*)(br + 32);
        f32x4 zc = {0.f,0.f,0.f,0.f};
        f32x4 cA = MFMA16(a0A, b0, zc);
        cA = MFMA16(a1A, b1, cA);
        f32x4 cB = MFMA16(a0B, b0, zc);
        cB = MFMA16(a1B, b1, cB);
        float bcv = bc[col];
        float ps = 0.f, pq = 0.f;
        #pragma unroll
        for (int r = 0; r < 4; ++r){
            float gA  = gt[(quad*4+r)*GTP + n];
            float xpA = gA*(cA[r] + bcv);
            float gB  = gt[(16+quad*4+r)*GTP + n];
            float xpB = gB*(cB[r] + bcv);
            ps += xpA + xpB; pq += xpA*xpA + xpB*xpB;
        }
        #pragma unroll
        for (int off = 32; off > 0; off >>= 1){
            ps += __shfl_xor(ps, off);
            pq += __shfl_xor(pq, off);
        }
        if (lane == 0){ snode[n] = ps; snode[64+n] = pq; }
    }
    __syncthreads();
    if (tid < 192){
        float v;
        if (tid < 128) v = snode[tid];
        else { int n = tid-128; v = entp[n]+entp[64+n]+entp[128+n]+entp[192+n]; }
        s3[(size_t)blockIdx.x*192 + tid] = v;
    }
}

// K5AB (fused k5a+k5b): 64 blocks; block n reduces s3 columns {n,64+n,128+n}
// over 1024 rows, then thread 0 runs node-n's regulator.
__global__ __launch_bounds__(256) void k5ab(const float* s3, const u16* basis,
    const u16* w1, const u16* b1, const u16* g, const u16* be, const u16* w2, const u16* b2,
    float* scal, void* dout)
{
    __shared__ double sred[12];
    int tid = threadIdx.x, n = blockIdx.x;
    int wave = tid >> 6, lane = tid & 63;
    double a0 = 0, a1 = 0, a2 = 0;
    for (int i = tid; i < 1024; i += 256){
        const float* r = s3 + (size_t)i*192;
        a0 += (double)r[n]; a1 += (double)r[64+n]; a2 += (double)r[128+n];
    }
    #pragma unroll
    for (int off = 32; off > 0; off >>= 1){
        a0 += __shfl_xor(a0, off);
        a1 += __shfl_xor(a1, off);
        a2 += __shfl_xor(a2, off);
    }
    if (lane == 0){ sred[wave*3] = a0; sred[wave*3+1] = a1; sred[wave*3+2] = a2; }
    __syncthreads();
    if (tid == 0){
        int isfp32 = scal[127] != 0.f;
        double sum = sred[0]+sred[3]+sred[6]+sred[9];
        double ssq = sred[1]+sred[4]+sred[7]+sred[10];
        double ent = sred[2]+sred[5]+sred[8]+sred[11];
        double Mn = 524288.0;
        float varn = (float)((ssq - sum*sum/Mn)/(Mn - 1.0));
        float entm = (float)(ent / 32768.0);
        float b0[16], b1v[16];
        for (int d = 0; d < 16; ++d){ b0[d] = bf2f(basis[d]); b1v[d] = bf2f(basis[16+d]); }
        float g00=0.f, g01=0.f, g11=0.f;
        for (int d = 0; d < 16; ++d){
            g00 += b0[d]*b0[d]; g01 += b0[d]*b1v[d]; g11 += b1v[d]*b1v[d];
        }
        float ortho = sqrtf((g00-1.f)*(g00-1.f) + 2.f*g01*g01 + (g11-1.f)*(g11-1.f));
        float sg[3] = {varn, entm, ortho};
        float o[3];
        run_regulator(w1,b1,g,be,w2,b2, sg, 3, o);
        scal[4+n] = o[0];
        if (n == 63){ scal[68] = entm;  store_out(dout, OUT_ENT,   entm,  isfp32); }
        if (n == 0) { scal[69] = ortho; store_out(dout, OUT_ORTHO, ortho, isfp32); }
    }
}

// k6 epilogue helper: gate/blend/stat/pack for one node-column, one stream.
__device__ __forceinline__ void k6_epi(unsigned gv, float fi, f32x4 c, f32x4 bcv,
    const float* b0d, const float* b1d, float& psum, float& pssq,
    unsigned& lo, unsigned& hi)
{
    float gate = bf2f((u16)(gv & 0xFFFFu));
    float w0v  = bf2f((u16)(gv >> 16));
    float Am = (1.f - fi)*gate;
    float fw0 = fi*w0v;
    float fw1 = fi - fw0;
    float xf[4];
    #pragma unroll
    for (int r = 0; r < 4; ++r){
        float base = fw0*b0d[r] + fw1*b1d[r];
        float v = Am*(c[r] + bcv[r]) + base;
        psum += v; pssq += v*v;
        xf[r] = v;
    }
    lo = (unsigned)f2bf(xf[0]) | ((unsigned)f2bf(xf[1]) << 16);
    hi = (unsigned)f2bf(xf[2]) | ((unsigned)f2bf(xf[3]) << 16);
}

// K6 v7: FOUR independent 16-row streams per wave (64 rows/wave).
// All wc/bc/wcat fragment loads shared across 4 streams (r8's lever, deeper).
// Grid 256 x 128 thr (2 waves, 128 rows/block). (128,2) -> 256-VGPR budget.
__global__ __launch_bounds__(128, 2) void k6_read(const u16* x, const unsigned* wpack,
    const u16* wc, const float* bc, const u16* wcatP,
    const u16* basis, const u16* bread, const float* scal,
    void* dout, float* hbuf, float* s4)
{
    __shared__ unsigned gwP[128*65];             // [128 rows][65] lo=gate, hi=w0, padded
    __shared__ float bc_s[1024];
    __shared__ float infl_s[64], b0s[16], b1s[16], brd[16];
    __shared__ float red[4];
    int tid = threadIdx.x;
    int isfp32 = scal[127] != 0.f;
    for (int i = tid; i < 8192; i += 128)
        gwP[(i >> 6)*65 + (i & 63)] = wpack[(size_t)blockIdx.x*8192 + i];
    for (int i = tid; i < 1024; i += 128) bc_s[i] = bc[i];
    if (tid < 64) infl_s[tid] = scal[4+tid];
    if (tid < 16){
        b0s[tid] = bf2f(basis[tid]);
        b1s[tid] = bf2f(basis[16+tid]);
        brd[tid] = (tid < 10) ? bf2f(bread[tid]) : 0.f;
    }
    __syncthreads();
    int wave = tid>>6, lane = tid&63;
    int m = lane&15, quad = lane>>4;
    int rowA = blockIdx.x*128 + wave*64 + m;
    const u16* xrA = x + (size_t)rowA*64 + quad*8;
    short8 a0A = *(const short8*)xrA,            a1A = *(const short8*)(xrA + 32);
    short8 a0B = *(const short8*)(xrA + 16*64),  a1B = *(const short8*)(xrA + 16*64 + 32);
    short8 a0C = *(const short8*)(xrA + 32*64),  a1C = *(const short8*)(xrA + 32*64 + 32);
    short8 a0D = *(const short8*)(xrA + 48*64),  a1D = *(const short8*)(xrA + 48*64 + 32);
    float b0d[4], b1d[4];
    #pragma unroll
    for (int r = 0; r < 4; ++r){ b0d[r] = b0s[quad*4+r]; b1d[r] = b1s[quad*4+r]; }
    const unsigned* gwA = gwP + (wave*64 + m)*65;
    const unsigned* gwB = gwA + 16*65;
    const unsigned* gwC = gwA + 32*65;
    const unsigned* gwD = gwA + 48*65;
    f32x4 acc0A = {0,0,0,0}, acc1A = {0,0,0,0};
    f32x4 acc0B = {0,0,0,0}, acc1B = {0,0,0,0};
    f32x4 acc0C = {0,0,0,0}, acc1C = {0,0,0,0};
    f32x4 acc0D = {0,0,0,0}, acc1D = {0,0,0,0};
    float psum = 0.f, pssq = 0.f;
    for (int c8 = 0; c8 < 8; ++c8){
        unsigned pdaA[8], pdbA[8], pdaB[8], pdbB[8];
        unsigned pdaC[8], pdbC[8], pdaD[8], pdbD[8];
        #pragma unroll
        for (int hf = 0; hf < 2; ++hf){
            short8 wf0[4], wf1[4];
            f32x4 bc4[4];
            float fiv[4];
            #pragma unroll
            for (int j = 0; j < 4; ++j){
                int n = c8*8 + hf*4 + j;
                int col = n*16 + m;
                const u16* br = wc + (size_t)col*64 + quad*8;
                wf0[j] = *(const short8*)br;
                wf1[j] = *(const short8*)(br + 32);
                bc4[j] = *(const f32x4*)(bc_s + n*16 + quad*4);
                fiv[j] = infl_s[n];
            }
            f32x4 cA[4], cB[4], cC[4], cD[4];
            #pragma unroll
            for (int j = 0; j < 4; ++j){
                f32x4 zc = {0.f,0.f,0.f,0.f};
                cA[j] = MFMA16(wf0[j], a0A, zc);
                cB[j] = MFMA16(wf0[j], a0B, zc);
                cC[j] = MFMA16(wf0[j], a0C, zc);
                cD[j] = MFMA16(wf0[j], a0D, zc);
            }
            #pragma unroll
            for (int j = 0; j < 4; ++j){
                cA[j] = MFMA16(wf1[j], a1A, cA[j]);
                cB[j] = MFMA16(wf1[j], a1B, cB[j]);
                cC[j] = MFMA16(wf1[j], a1C, cC[j]);
                cD[j] = MFMA16(wf1[j], a1D, cD[j]);
            }
            #pragma unroll
            for (int j = 0; j < 4; ++j){
                int t = hf*4 + j;
                int n = c8*8 + t;
                float fi = fiv[j];
                k6_epi(gwA[n], fi, cA[j], bc4[j], b0d, b1d, psum, pssq, pdaA[t], pdbA[t]);
                k6_epi(gwB[n], fi, cB[j], bc4[j], b0d, b1d, psum, pssq, pdaB[t], pdbB[t]);
                k6_epi(gwC[n], fi, cC[j], bc4[j], b0d, b1d, psum, pssq, pdaC[t], pdbC[t]);
                k6_epi(gwD[n], fi, cD[j], bc4[j], b0d, b1d, psum, pssq, pdaD[t], pdbD[t]);
            }
        }
        // GEMM2: A-frags from registers (per stream); wcat loads shared by 4.
        #pragma unroll
        for (int kk = 0; kk < 4; ++kk){
            short8 afA = __builtin_bit_cast(short8, make_int4((int)pdaA[2*kk], (int)pdbA[2*kk],
                                 (int)pdaA[2*kk+1], (int)pdbA[2*kk+1]));
            short8 afB = __builtin_bit_cast(short8, make_int4((int)pdaB[2*kk], (int)pdbB[2*kk],
                                 (int)pdaB[2*kk+1], (int)pdbB[2*kk+1]));
            short8 afC = __builtin_bit_cast(short8, make_int4((int)pdaC[2*kk], (int)pdbC[2*kk],
                                 (int)pdaC[2*kk+1], (int)pdbC[2*kk+1]));
            short8 afD = __builtin_bit_cast(short8, make_int4((int)pdaD[2*kk], (int)pdbD[2*kk],
                                 (int)pdaD[2*kk+1], (int)pdbD[2*kk+1]));
            const u16* wb = wcatP + m*1024 + c8*128 + kk*32 + quad*8;
            short8 bb0 = *(const short8*)wb;
            short8 bb1 = *(const short8*)(wb + 16*1024);
            acc0A = MFMA16(afA, bb0, acc0A);
            acc0B = MFMA16(afB, bb0, acc0B);
            acc0C = MFMA16(afC, bb0, acc0C);
            acc0D = MFMA16(afD, bb0, acc0D);
            acc1A = MFMA16(afA, bb1, acc1A);
            acc1B = MFMA16(afB, bb1, acc1B);
            acc1C = MFMA16(afC, bb1, acc1C);
            acc1D = MFMA16(afD, bb1, acc1D);
        }
    }
    int rowbase = blockIdx.x*128 + wave*64 + quad*4;
    #pragma unroll
    for (int r = 0; r < 4; ++r){
        int rowg = rowbase + r;
        if (m < 10) store_out(dout, rowg*10 + m, acc0A[r] + brd[m], isfp32);
        else        hbuf[rowg*8 + (m-10)] = fmaxf(acc0A[r], 0.f);
        if (m < 2)  hbuf[rowg*8 + 6 + m]  = fmaxf(acc1A[r], 0.f);
        rowg += 16;
        if (m < 10) store_out(dout, rowg*10 + m, acc0B[r] + brd[m], isfp32);
        else        hbuf[rowg*8 + (m-10)] = fmaxf(acc0B[r], 0.f);
        if (m < 2)  hbuf[rowg*8 + 6 + m]  = fmaxf(acc1B[r], 0.f);
        rowg += 16;
        if (m < 10) store_out(dout, rowg*10 + m, acc0C[r] + brd[m], isfp32);
        else        hbuf[rowg*8 + (m-10)] = fmaxf(acc0C[r], 0.f);
        if (m < 2)  hbuf[rowg*8 + 6 + m]  = fmaxf(acc1C[r], 0.f);
        rowg += 16;
        if (m < 10) store_out(dout, rowg*10 + m, acc0D[r] + brd[m], isfp32);
        else        hbuf[rowg*8 + (m-10)] = fmaxf(acc0D[r], 0.f);
        if (m < 2)  hbuf[rowg*8 + 6 + m]  = fmaxf(acc1D[r], 0.f);
    }
    #pragma unroll
    for (int off = 32; off > 0; off >>= 1){
        psum += __shfl_xor(psum, off);
        pssq += __shfl_xor(pssq, off);
    }
    if (lane == 0){ red[wave] = psum; red[2+wave] = pssq; }
    __syncthreads();
    if (tid == 0){
        s4[blockIdx.x*2]   = red[0]+red[1];
        s4[blockIdx.x*2+1] = red[2]+red[3];
    }
}

// K8: gain regulator (s4 256 rows x 2, redundantly per block) + proj
__global__ __launch_bounds__(256) void k8_proj(const float* hbuf, const u16* scw2,
    const u16* w1, const u16* b1, const u16* g, const u16* be, const u16* w2, const u16* b2,
    const float* s4, const float* scal, void* dout)
{
    __shared__ double sred[4];
    __shared__ float w2s[32];
    __shared__ float gains;
    int tid = threadIdx.x;
    int isfp32 = scal[127] != 0.f;
    if (tid < 32) w2s[tid] = bf2f(scw2[tid]);
    double s=0, ss=0;
    for (int i = tid; i < 256; i += 256){ s += (double)s4[i*2]; ss += (double)s4[i*2+1]; }
    double S  = blk_red(s,  sred, tid);
    double SS = blk_red(ss, sred, tid);
    if (tid == 0){
        double M = 33554432.0;
        float sg[2];
        sg[0] = (float)((SS - S*S/M)/(M - 1.0));
        sg[1] = scal[68];
        float o[3];
        run_regulator(w1,b1,g,be,w2,b2, sg, 2, o);
        gains = o[0];
    }
    __syncthreads();
    float gain = gains;
    int b = blockIdx.x*256 + tid;
    const float* h = hbuf + (size_t)b*8;
    float hv[8];
    #pragma unroll
    for (int k = 0; k < 8; ++k) hv[k] = h[k];
    #pragma unroll
    for (int i = 0; i < 4; ++i){
        float o = 0.f;
        #pragma unroll
        for (int k = 0; k < 8; ++k) o += hv[k]*w2s[i*8+k];
        store_out(dout, OUT_PROJ + b*4 + i, o*gain, isfp32);
    }
}

extern "C" void kernel_launch(void* const* d_in, const int* in_sizes, int n_in,
                              void* d_out, int out_size, void* d_ws, size_t ws_size,
                              hipStream_t stream)
{
    if (ws_size < WS_NEEDED) return;

    char* ws = (char*)d_ws;
    float* scal  = (float*)(ws + OFF_SCAL);
    u16*   adjb  = (u16*)  (ws + OFF_ADJ);
    float* beff  = (float*)(ws + OFF_BEFF);
    u16*   weff  = (u16*)  (ws + OFF_WEFF);
    u16*   wcat  = (u16*)  (ws + OFF_WCAT);
    float* s1    = (float*)(ws + OFF_S1);
    float* s2    = (float*)(ws + OFF_S2);
    float* s3    = (float*)(ws + OFF_S3);
    float* s4    = (float*)(ws + OFF_S4);
    float* hbuf  = (float*)(ws + OFF_H);
    unsigned* wpack = (unsigned*)(ws + OFF_W01);
    u16*   can   = (u16*)  (ws + OFF_CAN);
    u16*   bex   = (u16*)  (ws + OFF_BEX);
    u16*   wembT = (u16*)  (ws + OFF_WET);
    u16*   vw    = (u16*)  (ws + OFF_VW);
    float* vbias = (float*)(ws + OFF_VB);
    u16*   wc    = (u16*)  (ws + OFF_WC);
    u16*   sw    = (u16*)  (ws + OFF_SW);
    float* bc    = (float*)(ws + OFF_BC2);
    float* sb    = (float*)(ws + OFF_SB);

    static const int sidx[36] = {2,3,4,5,6,7,8,9,10,11,13,15,
        16,17,18,19,20,21, 22,23,24,25,26,27, 28,29,30,31,32,33, 34,35,36,37,38,39};
    static const int scnt[36] = {1024,4096,4096,256,256,16,1,256,32,256,32,10,
        48,16,16,16,48,3, 48,16,16,16,48,3, 48,16,16,16,48,3, 32,16,16,16,48,3};
    SmallTab t;
    const u16* canp[40];
    {
        int off = (int)CAN_SMALL;
        for (int j = 0; j < 36; ++j){
            t.src[j] = d_in[sidx[j]];
            t.cnt[j] = scnt[j];
            t.off[j] = off;
            canp[sidx[j]] = can + off;
            off += (scnt[j] + 7) & ~7;
        }
    }
    canp[0]  = can + CAN_X;
    canp[1]  = can + CAN_WEMB;
    canp[12] = can + CAN_SCW1;
    canp[14] = can + CAN_WREAD;

    const u16* pr_[6]; const u16* cr_[6]; const u16* sr_[6]; const u16* sc_[6];
    for (int i = 0; i < 6; ++i){
        pr_[i] = canp[16+i]; cr_[i] = canp[22+i];
        sr_[i] = canp[28+i]; sc_[i] = canp[34+i];
    }

    kc_all  <<<1425,256, 0, stream>>>(t, d_in[0], d_in[1], d_in[14], d_in[12],
                 d_in[5], d_in[7], can, scal, wcat, wembT, bex);
    k1_embed<<<1024,256, 0, stream>>>(canp[0], canp[1], canp[2], s1);
    k2_adj  <<<1,   256, 0, stream>>>(canp[3], canp[4], canp[2],
                 pr_[0],pr_[1],pr_[2],pr_[3],pr_[4],pr_[5], s1, scal, adjb, beff);
    k2b_mfma<<<64,  256, 0, stream>>>(adjb, wembT, weff);
    kvw     <<<260, 256, 0, stream>>>(canp[5], weff, beff, vw, vbias);
    k3_stats<<<1024,256, 0, stream>>>(canp[0], weff, beff, vw, vbias, s2);
    k3b_ctrl<<<1,   256, 0, stream>>>(canp[6], canp[5], canp[9], canp[11], canp[10],
                 cr_[0],cr_[1],cr_[2],cr_[3],cr_[4],cr_[5], s2, scal, bex);
    kbw     <<<312, 256, 0, stream>>>(bex, weff, beff, canp[8], wc, sw, bc, sb);
    k4_stats<<<1024,256, 0, stream>>>(canp[0], wc, sw, bc, sb, scal, wpack, s3);
    k5ab    <<<64,  256, 0, stream>>>(s3, canp[10],
                 sr_[0],sr_[1],sr_[2],sr_[3],sr_[4],sr_[5], scal, d_out);
    k6_read <<<256, 128, 0, stream>>>(canp[0], wpack, wc, bc, wcat, canp[10], canp[15],
                 scal, d_out, hbuf, s4);
    k8_proj <<<128, 256, 0, stream>>>(hbuf, canp[13],
                 sc_[0],sc_[1],sc_[2],sc_[3],sc_[4],sc_[5], s4, scal, d_out);
}

// Round 12
// 304.278 us; speedup vs baseline: 1.0823x; 1.0823x over previous
//
#include <hip/hip_runtime.h>

typedef unsigned short u16;
typedef unsigned long long u64;
typedef __attribute__((ext_vector_type(8))) short short8;
typedef __attribute__((ext_vector_type(4))) float f32x4;

#define MFMA16(a,b,c) __builtin_amdgcn_mfma_f32_16x16x32_bf16(a,b,c,0,0,0)

// ---- problem constants ----
#define B_SZ   32768
#define NNODE  64
#define NB_PAIR (B_SZ*NNODE)           // 2097152
#define OUT_PROJ   327680
#define OUT_ENT    458752
#define OUT_ORTHO  458753

// ---- workspace byte offsets ----
#define OFF_SCAL   ((size_t)0)                          // float[128]; [127] = isfp32
#define OFF_ADJ    ((size_t)512)                        // u16[4096] adjb
#define OFF_BEFF   (OFF_ADJ  + 8192u)                   // float[1024]
#define OFF_WEFF   (OFF_BEFF + 4096u)                   // u16[1024*64]
#define OFF_WCAT   (OFF_WEFF + 131072u)                 // u16[32*1024] (K-permuted)
#define OFF_S1     (OFF_WCAT + 65536u)                  // float[1024*3]
#define OFF_S2     (OFF_S1   + 12288u)                  // float[1024*3]
#define OFF_S3     (OFF_S2   + 12288u)                  // float[1024*192] (32-row blocks)
#define OFF_S4     (OFF_S3   + 2048u*192u*4u)           // float[512*2]
#define OFF_H      (OFF_S4   + 8192u)                   // float[32768*8]
#define OFF_W01    (OFF_H    + (size_t)B_SZ*8u*4u)      // u32[NB_PAIR] packed (w0|gate)
#define OFF_CAN    (OFF_W01  + (size_t)NB_PAIR*4u)      // canonical bf16 inputs

#define CAN_X      0u
#define CAN_WEMB   2097152u
#define CAN_WREAD  (CAN_WEMB + 65536u)
#define CAN_SCW1   (CAN_WREAD + 10240u)
#define CAN_SMALL  (CAN_SCW1 + 8192u)
#define CAN_TOTAL  (CAN_SMALL + 11008u)
#define OFF_BEX    (((OFF_CAN + (size_t)CAN_TOTAL*2u) + 63u) & ~(size_t)63u)
#define OFF_WET    (OFF_BEX + 48u*16u*2u)               // u16[1024*64] wembT
#define OFF_VW     (OFF_WET + 131072u)                  // u16[1024*64] Vw
#define OFF_VB     (OFF_VW  + 131072u)                  // float[1024] vbias
#define OFF_WC     (OFF_VB  + 4096u)                    // u16[1024*64] Wc
#define OFF_SW     (OFF_WC  + 131072u)                  // u16[192*64] Sw
#define OFF_BC2    (OFF_SW  + 24576u)                   // float[1024] bc
#define OFF_SB     (OFF_BC2 + 4096u)                    // float[192] sb
#define OFF_DR     (OFF_SB  + 1024u)                    // double[192] dred (unused, kept for layout)
#define WS_NEEDED  (OFF_DR  + 192u*8u)

__device__ __forceinline__ float bf2f(u16 u){
    unsigned v = ((unsigned)u) << 16;
    return __builtin_bit_cast(float, v);
}
__device__ __forceinline__ u16 f2bf(float f){
    unsigned u = __builtin_bit_cast(unsigned, f);
    u += 0x7FFFu + ((u >> 16) & 1u);           // RTN-even
    return (u16)(u >> 16);
}
__device__ __forceinline__ float sigm(float x){ return 1.f/(1.f + expf(-x)); }
__device__ __forceinline__ u16 conv_one(const void* src, int i, int isfp32){
    return isfp32 ? f2bf(((const float*)src)[i]) : ((const u16*)src)[i];
}
__device__ __forceinline__ void store_out(void* dout, int idx, float v, int isfp32){
    if (isfp32) ((float*)dout)[idx] = v;
    else        ((u16*)dout)[idx]   = f2bf(v);
}
__device__ __forceinline__ double blk_red(double v, double* sred, int tid){
    #pragma unroll
    for (int off = 32; off > 0; off >>= 1) v += __shfl_xor(v, off);
    if ((tid & 63) == 0) sred[tid >> 6] = v;
    __syncthreads();
    double r = sred[0] + sred[1] + sred[2] + sred[3];
    __syncthreads();
    return r;
}
// 4 independent block reductions sharing ONE barrier.
__device__ __forceinline__ void blk_red4(double* v, double* sred, int tid){
    #pragma unroll
    for (int off = 32; off > 0; off >>= 1){
        v[0] += __shfl_xor(v[0], off);
        v[1] += __shfl_xor(v[1], off);
        v[2] += __shfl_xor(v[2], off);
        v[3] += __shfl_xor(v[3], off);
    }
    if ((tid & 63) == 0){
        int w = tid >> 6;
        sred[w*4+0] = v[0]; sred[w*4+1] = v[1];
        sred[w*4+2] = v[2]; sred[w*4+3] = v[3];
    }
    __syncthreads();
    #pragma unroll
    for (int k = 0; k < 4; ++k)
        v[k] = sred[0*4+k] + sred[1*4+k] + sred[2*4+k] + sred[3*4+k];
    __syncthreads();
}

__device__ void run_regulator(const u16* w1, const u16* b1, const u16* g,
                              const u16* be, const u16* w2, const u16* b2,
                              const float* sig, int in_dim, float* out)
{
    float h[16];
    float mu = 0.f;
    for (int i = 0; i < 16; ++i){
        float a = bf2f(b1[i]);
        for (int j = 0; j < in_dim; ++j) a += sig[j]*bf2f(w1[i*in_dim + j]);
        h[i] = a; mu += a;
    }
    mu *= 0.0625f;
    float var = 0.f;
    for (int i = 0; i < 16; ++i){ float d = h[i]-mu; var += d*d; }
    var *= 0.0625f;
    float inv = 1.f / sqrtf(var + 1e-5f);
    for (int i = 0; i < 16; ++i){
        float hn = (h[i]-mu)*inv;
        h[i] = tanhf(hn*bf2f(g[i]) + bf2f(be[i]));
    }
    for (int c = 0; c < 3; ++c){
        float o = bf2f(b2[c]);
        for (int i = 0; i < 16; ++i) o += h[i]*bf2f(w2[c*16 + i]);
        out[c] = sigm(o);
    }
}

// per-block dtype probe (reads first 4KB of x, block-level reduction)
__device__ __forceinline__ int probe_isfp32(const u16* xraw, int tid, int* sred)
{
    int c = 0;
    #pragma unroll
    for (int j = 0; j < 4; ++j){
        u16 u = xraw[(tid*4 + j)*2];
        int e = (u >> 7) & 0xFF;
        if (u == 0 || (e >= 90 && e <= 140)) c++;
    }
    #pragma unroll
    for (int off = 32; off > 0; off >>= 1) c += __shfl_xor(c, off);
    if ((tid & 63) == 0) sred[tid >> 6] = c;
    __syncthreads();
    int tot = sred[0]+sred[1]+sred[2]+sred[3];
    __syncthreads();
    return tot < 614;
}

// vectorized big-copy: bf16 -> short8 passthrough; fp32 -> float4x2 + pack.
// nvec = count/8; identical values to conv_one per element.
__device__ __forceinline__ void copy_big(const void* src, u16* dst, int nvec,
                                         int gid, int stride, int isfp32)
{
    if (!isfp32){
        const short8* s = (const short8*)src;
        for (int i = gid; i < nvec; i += stride) *(short8*)(dst + i*8) = s[i];
    } else {
        const f32x4* s = (const f32x4*)src;
        for (int i = gid; i < nvec; i += stride){
            f32x4 v0 = s[i*2], v1 = s[i*2+1];
            u64 lo = (u64)f2bf(v0[0]) | ((u64)f2bf(v0[1])<<16) |
                     ((u64)f2bf(v0[2])<<32) | ((u64)f2bf(v0[3])<<48);
            u64 hi = (u64)f2bf(v1[0]) | ((u64)f2bf(v1[1])<<16) |
                     ((u64)f2bf(v1[2])<<32) | ((u64)f2bf(v1[3])<<48);
            *(u64*)(dst + i*8)     = lo;
            *(u64*)(dst + i*8 + 4) = hi;
        }
    }
}

// KC_ALL: single fused canonicalization launch (1425 blocks).
struct SmallTab { const void* src[36]; int cnt[36]; int off[36]; };
__global__ __launch_bounds__(256) void kc_all(SmallTab t,
    const void* x, const void* wemb, const void* wread_raw, const void* scw1_raw,
    const void* vslow_raw, const void* gatew_raw,
    u16* can, float* scal, u16* wcat, u16* wembT, u16* bex)
{
    __shared__ int sred[4];
    int b = blockIdx.x, tid = threadIdx.x;
    int isfp32 = probe_isfp32((const u16*)x, tid, sred);
    if (b == 0 && tid == 0) scal[127] = isfp32 ? 1.0f : 0.0f;
    if (b < 1024){
        int gid = b*256 + tid, stride = 1024*256;
        copy_big(x,         can + CAN_X,     262144, gid, stride, isfp32);
        copy_big(wemb,      can + CAN_WEMB,  8192,   gid, stride, isfp32);
        copy_big(wread_raw, can + CAN_WREAD, 1280,   gid, stride, isfp32);
        copy_big(scw1_raw,  can + CAN_SCW1,  1024,   gid, stride, isfp32);
    } else if (b < 1040){
        int gid = (b-1024)*256 + tid, stride = 16*256;
        for (int e = 0; e < 36; ++e){
            const void* s = t.src[e];
            u16* d = can + t.off[e];
            int n = t.cnt[e];
            for (int i = gid; i < n; i += stride) d[i] = conv_one(s, i, isfp32);
        }
    } else if (b < 1168){
        int idx = (b-1040)*256 + tid;
        int row = idx >> 10, k = idx & 1023;
        u16 v = 0;
        if (row < 10)      v = conv_one(wread_raw, row*1024 + k, isfp32);
        else if (row < 18) v = conv_one(scw1_raw, (row-10)*1024 + k, isfp32);
        int lo = k & 31;
        int khw = ((lo >> 2) & 3)*8 + ((lo >> 4) << 2) + (lo & 3);
        wcat[row*1024 + (k & ~31) + khw] = v;
    } else if (b < 1424){
        int idx = (b-1168)*256 + tid;
        int m = idx >> 10, jj = idx & 1023;
        wembT[jj*64 + m] = conv_one(wemb, m*1024 + jj, isfp32);
    } else {
        if (tid < 16){
            float a = 0.f;
            for (int i = 0; i < 16; ++i)
                a += bf2f(conv_one(gatew_raw, i, isfp32))*bf2f(conv_one(vslow_raw, i*16+tid, isfp32));
            bex[32*16+tid] = f2bf(a);
        }
    }
}

// K1 v2 (B-in-regs, wide): grid 1024 = 16 colgroups x 64 rowchunks.
__global__ __launch_bounds__(256) void k1_embed(const u16* x, const u16* wemb,
                                                const u16* bemb, float* s1)
{
    __shared__ float red[12];
    int tid = threadIdx.x, wave = tid>>6, lane = tid&63;
    int m = lane&15, quad = lane>>4;
    int cg = blockIdx.x & 15, rc = blockIdx.x >> 4;
    short8 b0[4], b1[4];
    float bias[4];
    #pragma unroll
    for (int s = 0; s < 4; ++s){
        int col = cg*64 + s*16 + m;
        b0[s] = *(const short8*)(wemb + col*64 + quad*8);
        b1[s] = *(const short8*)(wemb + col*64 + quad*8 + 32);
        bias[s] = bf2f(bemb[col]);
    }
    float sx = 0.f, sxx = 0.f, sabs = 0.f;
    const u16* xbase = x + (size_t)(rc*512 + wave*128 + m)*64 + quad*8;
    #pragma unroll 4
    for (int it = 0; it < 8; ++it){
        const u16* xr = xbase + (size_t)it*16*64;
        short8 a0 = *(const short8*)xr;
        short8 a1 = *(const short8*)(xr + 32);
        if (cg == 0){
            #pragma unroll
            for (int j = 0; j < 8; ++j){
                float f0 = bf2f((u16)a0[j]); sx += f0; sxx += f0*f0;
                float f1 = bf2f((u16)a1[j]); sx += f1; sxx += f1*f1;
            }
        }
        #pragma unroll
        for (int s = 0; s < 4; ++s){
            f32x4 zc = {0.f,0.f,0.f,0.f};
            f32x4 c = MFMA16(a0, b0[s], zc);
            c = MFMA16(a1, b1[s], c);
            #pragma unroll
            for (int r = 0; r < 4; ++r)
                sabs += fabsf(c[r]+bias[s]);
        }
    }
    #pragma unroll
    for (int off = 32; off > 0; off >>= 1){
        sx   += __shfl_xor(sx, off);
        sxx  += __shfl_xor(sxx, off);
        sabs += __shfl_xor(sabs, off);
    }
    if (lane == 0){ red[wave*3] = sx; red[wave*3+1] = sxx; red[wave*3+2] = sabs; }
    __syncthreads();
    if (tid == 0){
        for (int k = 0; k < 3; ++k)
            s1[blockIdx.x*3 + k] = red[k] + red[3+k] + red[6+k] + red[9+k];
    }
}

// K2: pr regulator -> pl0; build adjb + beff (single-barrier 4-way reduction)
__global__ __launch_bounds__(256) void k2_adj(const u16* adjw, const u16* adjm, const u16* bemb,
    const u16* w1, const u16* b1, const u16* g, const u16* be, const u16* w2, const u16* b2,
    const float* s1, float* scal, u16* adjb, float* beff)
{
    __shared__ double sred[16];
    __shared__ float raw[4096];
    __shared__ float rowsum[64];
    __shared__ float bembs[1024];
    __shared__ float pl0s;
    int tid = threadIdx.x;
    for (int i = tid; i < 1024; i += 256) bembs[i] = bf2f(bemb[i]);
    double v[4] = {0,0,0,0};
    for (int i = tid; i < 1024; i += 256){
        v[0] += (double)s1[i*3]; v[1] += (double)s1[i*3+1]; v[2] += (double)s1[i*3+2];
    }
    for (int i = tid; i < 4096; i += 256){ float f = bf2f(adjw[i]); v[3] += (double)(f*f); }
    blk_red4(v, sred, tid);
    if (tid == 0){
        double nx = 2097152.0;
        float sg[3];
        sg[0] = (float)((v[1] - v[0]*v[0]/nx)/(nx - 1.0));
        sg[1] = (float)(v[2] / 33554432.0);
        sg[2] = sqrtf((float)v[3]);
        float o[3];
        run_regulator(w1,b1,g,be,w2,b2, sg, 3, o);
        scal[0] = o[0]; pl0s = o[0];
    }
    __syncthreads();
    float pl0 = pl0s;
    for (int i = tid; i < 4096; i += 256)
        raw[i] = sigm(bf2f(adjw[i])*pl0) * bf2f(adjm[i]);
    __syncthreads();
    if (tid < 64){
        float r = 0.f;
        for (int mc = 0; mc < 64; ++mc) r += raw[tid*64 + mc];
        rowsum[tid] = fmaxf(r, 1e-6f);
    }
    __syncthreads();
    for (int i = tid; i < 4096; i += 256) adjb[i] = f2bf(raw[i] / rowsum[i>>6]);
    for (int o = tid; o < 1024; o += 256){
        int n = o >> 4, d = o & 15;
        float a = 0.f;
        for (int m = 0; m < 64; ++m) a += raw[n*64+m]*bembs[m*16+d];
        beff[o] = a / rowsum[n];
    }
}

// K2b (MFMA): Weff = adjb @ Wr
__global__ __launch_bounds__(256) void k2b_mfma(const u16* adjb, const u16* wembT, u16* weff)
{
    int tid = threadIdx.x, wave = tid>>6, lane = tid&63;
    int m = lane&15, quad = lane>>4;
    const u16* ar = adjb + (wave*16 + m)*64 + quad*8;
    short8 a0 = *(const short8*)ar;
    short8 a1 = *(const short8*)(ar + 32);
    int col = blockIdx.x*16 + m;
    const u16* br = wembT + col*64 + quad*8;
    short8 b0 = *(const short8*)br;
    short8 b1 = *(const short8*)(br + 32);
    f32x4 acc = {0.f,0.f,0.f,0.f};
    acc = MFMA16(a0, b0, acc);
    acc = MFMA16(a1, b1, acc);
    #pragma unroll
    for (int r = 0; r < 4; ++r)
        weff[(size_t)(wave*16 + quad*4 + r)*1024 + blockIdx.x*16 + m] = f2bf(acc[r]);
}

// KVW: Vw = V@Weff (per node), vbias = V@beff
__global__ __launch_bounds__(256) void kvw(const u16* vslow, const u16* weff, const float* beff,
                                           u16* vw, float* vbias)
{
    __shared__ float Vs[256];
    int tid = threadIdx.x, b = blockIdx.x;
    Vs[tid] = bf2f(vslow[tid]);
    __syncthreads();
    if (b < 256){
        int idx = b*256 + tid;
        int j = idx >> 6, kf = idx & 63;
        int n = j >> 4, i = j & 15;
        float a = 0.f;
        #pragma unroll
        for (int d = 0; d < 16; ++d) a += Vs[i*16+d]*bf2f(weff[(size_t)(n*16+d)*64 + kf]);
        vw[(size_t)j*64 + kf] = f2bf(a);
    } else {
        int o = (b-256)*256 + tid;
        int n = o >> 4, i = o & 15;
        float a = 0.f;
        #pragma unroll
        for (int d = 0; d < 16; ++d) a += Vs[i*16+d]*beff[n*16+d];
        vbias[o] = a;
    }
}

// K3 v2 (B-in-regs, wide): grid 1024 = 16 colgroups x 64 rowchunks.
__global__ __launch_bounds__(256) void k3_stats(const u16* x, const u16* weff, const float* beff,
                                                const u16* vw, const float* vbias, float* s2)
{
    __shared__ float red[12];
    int tid = threadIdx.x, wave = tid>>6, lane = tid&63;
    int m = lane&15, quad = lane>>4;
    int cg = blockIdx.x & 15, rc = blockIdx.x >> 4;
    short8 wb0[4], wb1[4], vb0[4], vb1[4];
    float bev[4], vbv[4];
    #pragma unroll
    for (int s = 0; s < 4; ++s){
        int col = cg*64 + s*16 + m;
        wb0[s] = *(const short8*)(weff + (size_t)col*64 + quad*8);
        wb1[s] = *(const short8*)(weff + (size_t)col*64 + quad*8 + 32);
        vb0[s] = *(const short8*)(vw + (size_t)col*64 + quad*8);
        vb1[s] = *(const short8*)(vw + (size_t)col*64 + quad*8 + 32);
        bev[s] = beff[col];
        vbv[s] = vbias[col];
    }
    float psum=0.f, pssq=0.f, pabsv=0.f;
    const u16* xbase = x + (size_t)(rc*512 + wave*128 + m)*64 + quad*8;
    #pragma unroll 4
    for (int it = 0; it < 8; ++it){
        const u16* xr = xbase + (size_t)it*16*64;
        short8 a0 = *(const short8*)xr;
        short8 a1 = *(const short8*)(xr + 32);
        #pragma unroll
        for (int s = 0; s < 4; ++s){
            f32x4 zc = {0.f,0.f,0.f,0.f};
            f32x4 c = MFMA16(a0, wb0[s], zc);
            c = MFMA16(a1, wb1[s], c);
            f32x4 w = MFMA16(a0, vb0[s], zc);
            w = MFMA16(a1, vb1[s], w);
            #pragma unroll
            for (int r = 0; r < 4; ++r){
                float f0 = c[r] + bev[s];
                psum += f0; pssq += f0*f0;
                pabsv += fabsf(w[r] + vbv[s]);
            }
        }
    }
    #pragma unroll
    for (int off = 32; off > 0; off >>= 1){
        psum  += __shfl_xor(psum, off);
        pssq  += __shfl_xor(pssq, off);
        pabsv += __shfl_xor(pabsv, off);
    }
    if (lane == 0){ red[wave*3] = psum; red[wave*3+1] = pssq; red[wave*3+2] = pabsv; }
    __syncthreads();
    if (tid == 0){
        for (int k = 0; k < 3; ++k)
            s2[blockIdx.x*3 + k] = red[k] + red[3+k] + red[6+k] + red[9+k];
    }
}

// K3b: ctrl regulator + build bex dynamic rows (single-barrier 4-way reduction)
__global__ __launch_bounds__(256) void k3b_ctrl(const u16* wslow,
    const u16* vslow, const u16* wfast, const u16* wq, const u16* basis,
    const u16* w1, const u16* b1, const u16* g, const u16* be, const u16* w2, const u16* b2,
    const float* s2, float* scal, u16* bex)
{
    __shared__ double sred[16];
    __shared__ float ctrl2s;
    int tid = threadIdx.x;
    double v[4] = {0,0,0,0};
    for (int i = tid; i < 1024; i += 256){
        v[0] += (double)s2[i*3]; v[1] += (double)s2[i*3+1]; v[2] += (double)s2[i*3+2];
    }
    float wf = bf2f(wslow[tid]);
    v[3] = (double)(wf*wf);
    blk_red4(v, sred, tid);
    if (tid == 0){
        double M = 33554432.0;
        float sg[3];
        sg[0] = (float)((v[1] - v[0]*v[0]/M)/(M - 1.0));
        sg[1] = (float)(v[2] / M);
        sg[2] = sqrtf((float)v[3]);
        float o[3];
        run_regulator(w1,b1,g,be,w2,b2, sg, 3, o);
        scal[1] = o[0]; scal[2] = o[2];
        ctrl2s = o[2];
    }
    __syncthreads();
    float ctrl2 = ctrl2s;
    if (tid < 64){
        #pragma unroll
        for (int j = 0; j < 4; ++j){
            int idx = tid*4 + j;
            int d = idx >> 4, k = idx & 15;
            bex[(16+d)*16+k] = f2bf(bf2f(vslow[idx]) + ctrl2*bf2f(wfast[idx]));
        }
    } else if (tid < 96){
        int a = (tid-64) >> 4, k = (tid-64) & 15;
        float e = 0.f;
        for (int d = 0; d < 16; ++d){
            float bq = 0.f;
            for (int j = 0; j < 16; ++j) bq += bf2f(basis[a*16+j])*bf2f(wq[j*16+d]);
            e += bq*(bf2f(vslow[d*16+k]) + ctrl2*bf2f(wfast[d*16+k]));
        }
        bex[(33+a)*16+k] = f2bf(0.25f*e);
    }
}

// KBW: build Wc[(n,d)][64], Sw[(n,j)][64], bc[1024], sb[192]
__global__ __launch_bounds__(256) void kbw(const u16* bex, const u16* weff, const float* beff,
                                           const u16* gateb, u16* wc, u16* sw,
                                           float* bc, float* sb)
{
    __shared__ float BcL[256], gvL[16], e0L[16], e1L[16];
    int tid = threadIdx.x;
    if (tid < 256) BcL[tid] = bf2f(bex[(16 + (tid>>4))*16 + (tid&15)]);
    if (tid < 16){
        gvL[tid] = bf2f(bex[32*16+tid]);
        e0L[tid] = bf2f(bex[33*16+tid]);
        e1L[tid] = bf2f(bex[34*16+tid]);
    }
    __syncthreads();
    int id = blockIdx.x*256 + tid;
    if (id < 65536){
        int col = id >> 6, k = id & 63;
        int n = col >> 4, d = col & 15;
        float a = 0.f;
        #pragma unroll
        for (int dd = 0; dd < 16; ++dd)
            a += BcL[d*16+dd]*bf2f(weff[(size_t)(n*16+dd)*64 + k]);
        wc[(size_t)col*64 + k] = f2bf(a);
    } else if (id < 77824){
        int j2 = id - 65536;
        int scol = j2 >> 6, k = j2 & 63;
        int n = scol/3, j = scol - n*3;
        const float* sr = (j==0) ? gvL : (j==1) ? e0L : e1L;
        float a = 0.f;
        #pragma unroll
        for (int dd = 0; dd < 16; ++dd)
            a += sr[dd]*bf2f(weff[(size_t)(n*16+dd)*64 + k]);
        sw[(size_t)scol*64 + k] = f2bf(a);
    } else if (id < 78848){
        int col = id - 77824;
        int n = col >> 4, d = col & 15;
        float a = 0.f;
        #pragma unroll
        for (int dd = 0; dd < 16; ++dd) a += BcL[d*16+dd]*beff[n*16+dd];
        bc[col] = a;
    } else if (id < 79040){
        int s = id - 78848;
        int n = s/3, j = s - n*3;
        const float* sr = (j==0) ? gvL : (j==1) ? e0L : e1L;
        float a = 0.f;
        #pragma unroll
        for (int dd = 0; dd < 16; ++dd) a += sr[dd]*beff[n*16+dd];
        if (j == 0) a += bf2f(gateb[0]);
        sb[s] = a;
    }
}

// K4_stats v2: TWO 16-row streams per block (32 rows), sharing all sw/wc
// fragment loads. gt pitch 65 (conflict-free). 1024 blocks x 256 thr.
#define SCP 193
#define GTP 65
__global__ __launch_bounds__(256) void k4_stats(const u16* x, const u16* wc, const u16* sw,
    const float* bc, const float* sb, const float* scal, unsigned* wpack, float* s3)
{
    __shared__ float sc[32*SCP];
    __shared__ float gt[32*GTP];
    __shared__ float entp[256];
    __shared__ float snode[128];
    int tid = threadIdx.x, wave = tid>>6, lane = tid&63;
    int m = lane&15, quad = lane>>4;
    int row0 = blockIdx.x*32;
    const u16* xrA = x + (size_t)(row0 + m)*64 + quad*8;
    short8 a0A = *(const short8*)xrA;
    short8 a1A = *(const short8*)(xrA + 32);
    const u16* xrB = xrA + 16*64;
    short8 a0B = *(const short8*)xrB;
    short8 a1B = *(const short8*)(xrB + 32);
    float ctrl0 = scal[1];
    #pragma unroll
    for (int tt = 0; tt < 3; ++tt){
        int ct = wave*3 + tt;
        int scol = ct*16 + m;
        const u16* br = sw + (size_t)scol*64 + quad*8;
        short8 b0 = *(const short8*)br;
        short8 b1 = *(const short8*)(br + 32);
        f32x4 zc = {0.f,0.f,0.f,0.f};
        f32x4 cA = MFMA16(a0A, b0, zc);
        cA = MFMA16(a1A, b1, cA);
        f32x4 cB = MFMA16(a0B, b0, zc);
        cB = MFMA16(a1B, b1, cB);
        float sbv = sb[scol];
        #pragma unroll
        for (int r = 0; r < 4; ++r){
            sc[(quad*4+r)*SCP + scol]      = cA[r] + sbv;
            sc[(16+quad*4+r)*SCP + scol]   = cB[r] + sbv;
        }
    }
    __syncthreads();
    {
        int n = tid & 63, rgrp = tid >> 6;
        float ent = 0.f;
        #pragma unroll
        for (int rr = 0; rr < 8; ++rr){
            int row = rgrp*8 + rr;
            float gd  = sc[row*SCP + 3*n];
            float e0d = sc[row*SCP + 3*n + 1];
            float e1d = sc[row*SCP + 3*n + 2];
            float gate = ctrl0 / (1.f + __expf(-gd));
            float l0 = gate*e0d, l1 = gate*e1d;
            float w1v = 1.f/(1.f + __expf(l0 - l1));
            float w0v = 1.f - w1v;
            ent += -(w0v*__logf(w0v + 1e-8f) + w1v*__logf(w1v + 1e-8f));
            gt[row*GTP + n] = gate;
            wpack[(size_t)(row0 + row)*64 + n] =
                ((unsigned)f2bf(w0v) << 16) | (unsigned)f2bf(gate);
        }
        entp[tid] = ent;
    }
    __syncthreads();
    #pragma unroll
    for (int tt = 0; tt < 16; ++tt){
        int n = wave*16 + tt;
        int col = n*16 + m;
        const u16* br = wc + (size_t)col*64 + quad*8;
        short8 b0 = *(const short8*)br;
        short8 b1 = *(const short8*)(br + 32);
        f32x4 zc = {0.f,0.f,0.f,0.f};
        f32x4 cA = MFMA16(a0A, b0, zc);
        cA = MFMA16(a1A, b1, cA);
        f32x4 cB = MFMA16(a0B, b0, zc);
        cB = MFMA16(a1B, b1, cB);
        float bcv = bc[col];
        float ps = 0.f, pq = 0.f;
        #pragma unroll
        for (int r = 0; r < 4; ++r){
            float gA  = gt[(quad*4+r)*GTP + n];
            float xpA = gA*(cA[r] + bcv);
            float gB  = gt[(16+quad*4+r)*GTP + n];
            float xpB = gB*(cB[r] + bcv);
            ps += xpA + xpB; pq += xpA*xpA + xpB*xpB;
        }
        #pragma unroll
        for (int off = 32; off > 0; off >>= 1){
            ps += __shfl_xor(ps, off);
            pq += __shfl_xor(pq, off);
        }
        if (lane == 0){ snode[n] = ps; snode[64+n] = pq; }
    }
    __syncthreads();
    if (tid < 192){
        float v;
        if (tid < 128) v = snode[tid];
        else { int n = tid-128; v = entp[n]+entp[64+n]+entp[128+n]+entp[192+n]; }
        s3[(size_t)blockIdx.x*192 + tid] = v;
    }
}

// K5AB (fused k5a+k5b): 64 blocks; block n reduces s3 columns {n,64+n,128+n}
// over 1024 rows, then thread 0 runs node-n's regulator.
__global__ __launch_bounds__(256) void k5ab(const float* s3, const u16* basis,
    const u16* w1, const u16* b1, const u16* g, const u16* be, const u16* w2, const u16* b2,
    float* scal, void* dout)
{
    __shared__ double sred[12];
    int tid = threadIdx.x, n = blockIdx.x;
    int wave = tid >> 6, lane = tid & 63;
    double a0 = 0, a1 = 0, a2 = 0;
    for (int i = tid; i < 1024; i += 256){
        const float* r = s3 + (size_t)i*192;
        a0 += (double)r[n]; a1 += (double)r[64+n]; a2 += (double)r[128+n];
    }
    #pragma unroll
    for (int off = 32; off > 0; off >>= 1){
        a0 += __shfl_xor(a0, off);
        a1 += __shfl_xor(a1, off);
        a2 += __shfl_xor(a2, off);
    }
    if (lane == 0){ sred[wave*3] = a0; sred[wave*3+1] = a1; sred[wave*3+2] = a2; }
    __syncthreads();
    if (tid == 0){
        int isfp32 = scal[127] != 0.f;
        double sum = sred[0]+sred[3]+sred[6]+sred[9];
        double ssq = sred[1]+sred[4]+sred[7]+sred[10];
        double ent = sred[2]+sred[5]+sred[8]+sred[11];
        double Mn = 524288.0;
        float varn = (float)((ssq - sum*sum/Mn)/(Mn - 1.0));
        float entm = (float)(ent / 32768.0);
        float b0[16], b1v[16];
        for (int d = 0; d < 16; ++d){ b0[d] = bf2f(basis[d]); b1v[d] = bf2f(basis[16+d]); }
        float g00=0.f, g01=0.f, g11=0.f;
        for (int d = 0; d < 16; ++d){
            g00 += b0[d]*b0[d]; g01 += b0[d]*b1v[d]; g11 += b1v[d]*b1v[d];
        }
        float ortho = sqrtf((g00-1.f)*(g00-1.f) + 2.f*g01*g01 + (g11-1.f)*(g11-1.f));
        float sg[3] = {varn, entm, ortho};
        float o[3];
        run_regulator(w1,b1,g,be,w2,b2, sg, 3, o);
        scal[4+n] = o[0];
        if (n == 63){ scal[68] = entm;  store_out(dout, OUT_ENT,   entm,  isfp32); }
        if (n == 0) { scal[69] = ortho; store_out(dout, OUT_ORTHO, ortho, isfp32); }
    }
}

// K6 (r10 best): TWO independent 16-row streams per wave (32 rows/wave).
// wc & wcat fragment loads are SHARED between streams.
// Grid 512 x 128 thr (2 waves, 64 rows/block).
__global__ __launch_bounds__(128, 2) void k6_read(const u16* x, const unsigned* wpack,
    const u16* wc, const float* bc, const u16* wcatP,
    const u16* basis, const u16* bread, const float* scal,
    void* dout, float* hbuf, float* s4)
{
    __shared__ unsigned gwP[64*65];              // [64 rows][65] lo=gate, hi=w0, padded
    __shared__ float bc_s[1024];
    __shared__ float infl_s[64], b0s[16], b1s[16], brd[16];
    __shared__ float red[4];
    int tid = threadIdx.x;
    int isfp32 = scal[127] != 0.f;
    for (int i = tid; i < 4096; i += 128)
        gwP[(i >> 6)*65 + (i & 63)] = wpack[(size_t)blockIdx.x*4096 + i];
    for (int i = tid; i < 1024; i += 128) bc_s[i] = bc[i];
    if (tid < 64) infl_s[tid] = scal[4+tid];
    if (tid < 16){
        b0s[tid] = bf2f(basis[tid]);
        b1s[tid] = bf2f(basis[16+tid]);
        brd[tid] = (tid < 10) ? bf2f(bread[tid]) : 0.f;
    }
    __syncthreads();
    int wave = tid>>6, lane = tid&63;
    int m = lane&15, quad = lane>>4;
    int rowA = blockIdx.x*64 + wave*32 + m;      // stream A rows [base, base+16)
    const u16* xrA = x + (size_t)rowA*64 + quad*8;
    short8 a0A = *(const short8*)xrA;
    short8 a1A = *(const short8*)(xrA + 32);
    const u16* xrB = xrA + 16*64;                // stream B rows [base+16, base+32)
    short8 a0B = *(const short8*)xrB;
    short8 a1B = *(const short8*)(xrB + 32);
    float b0d[4], b1d[4];
    #pragma unroll
    for (int r = 0; r < 4; ++r){ b0d[r] = b0s[quad*4+r]; b1d[r] = b1s[quad*4+r]; }
    const unsigned* gwA = gwP + (wave*32 + m)*65;
    const unsigned* gwB = gwA + 16*65;
    f32x4 acc0A = {0.f,0.f,0.f,0.f}, acc1A = {0.f,0.f,0.f,0.f};
    f32x4 acc0B = {0.f,0.f,0.f,0.f}, acc1B = {0.f,0.f,0.f,0.f};
    float psum = 0.f, pssq = 0.f;
    for (int c8 = 0; c8 < 8; ++c8){
        unsigned pdaA[8], pdbA[8], pdaB[8], pdbB[8];
        #pragma unroll
        for (int hf = 0; hf < 2; ++hf){
            short8 wf0[4], wf1[4];
            f32x4 bc4[4];
            unsigned gvA[4], gvB[4];
            float fiv[4];
            #pragma unroll
            for (int j = 0; j < 4; ++j){
                int n = c8*8 + hf*4 + j;
                int col = n*16 + m;
                const u16* br = wc + (size_t)col*64 + quad*8;
                wf0[j] = *(const short8*)br;
                wf1[j] = *(const short8*)(br + 32);
                bc4[j] = *(const f32x4*)(bc_s + n*16 + quad*4);
                gvA[j] = gwA[n];
                gvB[j] = gwB[n];
                fiv[j] = infl_s[n];
            }
            f32x4 cA[4], cB[4];
            #pragma unroll
            for (int j = 0; j < 4; ++j){
                f32x4 zc = {0.f,0.f,0.f,0.f};
                cA[j] = MFMA16(wf0[j], a0A, zc);   // swapped: lane=row, dims quad*4+r
                cB[j] = MFMA16(wf0[j], a0B, zc);
            }
            #pragma unroll
            for (int j = 0; j < 4; ++j){
                cA[j] = MFMA16(wf1[j], a1A, cA[j]);
                cB[j] = MFMA16(wf1[j], a1B, cB[j]);
            }
            #pragma unroll
            for (int j = 0; j < 4; ++j){
                int t = hf*4 + j;
                float fi = fiv[j];
                {   // stream A epilogue
                    float gate = bf2f((u16)(gvA[j] & 0xFFFFu));
                    float w0v  = bf2f((u16)(gvA[j] >> 16));
                    float Am   = (1.f - fi)*gate;
                    float fw0 = fi*w0v;
                    float fw1 = fi - fw0;
                    float xf[4];
                    #pragma unroll
                    for (int r = 0; r < 4; ++r){
                        float base = fw0*b0d[r] + fw1*b1d[r];
                        float v = Am*(cA[j][r] + bc4[j][r]) + base;
                        psum += v; pssq += v*v;
                        xf[r] = v;
                    }
                    pdaA[t] = (unsigned)f2bf(xf[0]) | ((unsigned)f2bf(xf[1]) << 16);
                    pdbA[t] = (unsigned)f2bf(xf[2]) | ((unsigned)f2bf(xf[3]) << 16);
                }
                {   // stream B epilogue
                    float gate = bf2f((u16)(gvB[j] & 0xFFFFu));
                    float w0v  = bf2f((u16)(gvB[j] >> 16));
                    float Am   = (1.f - fi)*gate;
                    float fw0 = fi*w0v;
                    float fw1 = fi - fw0;
                    float xf[4];
                    #pragma unroll
                    for (int r = 0; r < 4; ++r){
                        float base = fw0*b0d[r] + fw1*b1d[r];
                        float v = Am*(cB[j][r] + bc4[j][r]) + base;
                        psum += v; pssq += v*v;
                        xf[r] = v;
                    }
                    pdaB[t] = (unsigned)f2bf(xf[0]) | ((unsigned)f2bf(xf[1]) << 16);
                    pdbB[t] = (unsigned)f2bf(xf[2]) | ((unsigned)f2bf(xf[3]) << 16);
                }
            }
        }
        // GEMM2: A-frags from registers (per stream); B loads SHARED.
        #pragma unroll
        for (int kk = 0; kk < 4; ++kk){
            int4 awA = make_int4((int)pdaA[2*kk], (int)pdbA[2*kk],
                                 (int)pdaA[2*kk+1], (int)pdbA[2*kk+1]);
            int4 awB = make_int4((int)pdaB[2*kk], (int)pdbB[2*kk],
                                 (int)pdaB[2*kk+1], (int)pdbB[2*kk+1]);
            short8 afA = __builtin_bit_cast(short8, awA);
            short8 afB = __builtin_bit_cast(short8, awB);
            const u16* wb = wcatP + m*1024 + c8*128 + kk*32 + quad*8;
            short8 bb0 = *(const short8*)wb;
            short8 bb1 = *(const short8*)(wb + 16*1024);
            acc0A = MFMA16(afA, bb0, acc0A);
            acc0B = MFMA16(afB, bb0, acc0B);
            acc1A = MFMA16(afA, bb1, acc1A);
            acc1B = MFMA16(afB, bb1, acc1B);
        }
    }
    int rowbaseA = blockIdx.x*64 + wave*32 + quad*4;
    #pragma unroll
    for (int r = 0; r < 4; ++r){
        int rowgA = rowbaseA + r;
        if (m < 10) store_out(dout, rowgA*10 + m, acc0A[r] + brd[m], isfp32);
        else        hbuf[rowgA*8 + (m-10)] = fmaxf(acc0A[r], 0.f);
        if (m < 2)  hbuf[rowgA*8 + 6 + m]  = fmaxf(acc1A[r], 0.f);
        int rowgB = rowgA + 16;
        if (m < 10) store_out(dout, rowgB*10 + m, acc0B[r] + brd[m], isfp32);
        else        hbuf[rowgB*8 + (m-10)] = fmaxf(acc0B[r], 0.f);
        if (m < 2)  hbuf[rowgB*8 + 6 + m]  = fmaxf(acc1B[r], 0.f);
    }
    #pragma unroll
    for (int off = 32; off > 0; off >>= 1){
        psum += __shfl_xor(psum, off);
        pssq += __shfl_xor(pssq, off);
    }
    if (lane == 0){ red[wave] = psum; red[2+wave] = pssq; }
    __syncthreads();
    if (tid == 0){
        s4[blockIdx.x*2]   = red[0]+red[1];
        s4[blockIdx.x*2+1] = red[2]+red[3];
    }
}

// K8: gain regulator (s4 512 rows x 2, redundantly per block) + proj
__global__ __launch_bounds__(256) void k8_proj(const float* hbuf, const u16* scw2,
    const u16* w1, const u16* b1, const u16* g, const u16* be, const u16* w2, const u16* b2,
    const float* s4, const float* scal, void* dout)
{
    __shared__ double sred[4];
    __shared__ float w2s[32];
    __shared__ float gains;
    int tid = threadIdx.x;
    int isfp32 = scal[127] != 0.f;
    if (tid < 32) w2s[tid] = bf2f(scw2[tid]);
    double s=0, ss=0;
    for (int i = tid; i < 512; i += 256){ s += (double)s4[i*2]; ss += (double)s4[i*2+1]; }
    double S  = blk_red(s,  sred, tid);
    double SS = blk_red(ss, sred, tid);
    if (tid == 0){
        double M = 33554432.0;
        float sg[2];
        sg[0] = (float)((SS - S*S/M)/(M - 1.0));
        sg[1] = scal[68];
        float o[3];
        run_regulator(w1,b1,g,be,w2,b2, sg, 2, o);
        gains = o[0];
    }
    __syncthreads();
    float gain = gains;
    int b = blockIdx.x*256 + tid;
    const float* h = hbuf + (size_t)b*8;
    float hv[8];
    #pragma unroll
    for (int k = 0; k < 8; ++k) hv[k] = h[k];
    #pragma unroll
    for (int i = 0; i < 4; ++i){
        float o = 0.f;
        #pragma unroll
        for (int k = 0; k < 8; ++k) o += hv[k]*w2s[i*8+k];
        store_out(dout, OUT_PROJ + b*4 + i, o*gain, isfp32);
    }
}

extern "C" void kernel_launch(void* const* d_in, const int* in_sizes, int n_in,
                              void* d_out, int out_size, void* d_ws, size_t ws_size,
                              hipStream_t stream)
{
    if (ws_size < WS_NEEDED) return;

    char* ws = (char*)d_ws;
    float* scal  = (float*)(ws + OFF_SCAL);
    u16*   adjb  = (u16*)  (ws + OFF_ADJ);
    float* beff  = (float*)(ws + OFF_BEFF);
    u16*   weff  = (u16*)  (ws + OFF_WEFF);
    u16*   wcat  = (u16*)  (ws + OFF_WCAT);
    float* s1    = (float*)(ws + OFF_S1);
    float* s2    = (float*)(ws + OFF_S2);
    float* s3    = (float*)(ws + OFF_S3);
    float* s4    = (float*)(ws + OFF_S4);
    float* hbuf  = (float*)(ws + OFF_H);
    unsigned* wpack = (unsigned*)(ws + OFF_W01);
    u16*   can   = (u16*)  (ws + OFF_CAN);
    u16*   bex   = (u16*)  (ws + OFF_BEX);
    u16*   wembT = (u16*)  (ws + OFF_WET);
    u16*   vw    = (u16*)  (ws + OFF_VW);
    float* vbias = (float*)(ws + OFF_VB);
    u16*   wc    = (u16*)  (ws + OFF_WC);
    u16*   sw    = (u16*)  (ws + OFF_SW);
    float* bc    = (float*)(ws + OFF_BC2);
    float* sb    = (float*)(ws + OFF_SB);

    static const int sidx[36] = {2,3,4,5,6,7,8,9,10,11,13,15,
        16,17,18,19,20,21, 22,23,24,25,26,27, 28,29,30,31,32,33, 34,35,36,37,38,39};
    static const int scnt[36] = {1024,4096,4096,256,256,16,1,256,32,256,32,10,
        48,16,16,16,48,3, 48,16,16,16,48,3, 48,16,16,16,48,3, 32,16,16,16,48,3};
    SmallTab t;
    const u16* canp[40];
    {
        int off = (int)CAN_SMALL;
        for (int j = 0; j < 36; ++j){
            t.src[j] = d_in[sidx[j]];
            t.cnt[j] = scnt[j];
            t.off[j] = off;
            canp[sidx[j]] = can + off;
            off += (scnt[j] + 7) & ~7;
        }
    }
    canp[0]  = can + CAN_X;
    canp[1]  = can + CAN_WEMB;
    canp[12] = can + CAN_SCW1;
    canp[14] = can + CAN_WREAD;

    const u16* pr_[6]; const u16* cr_[6]; const u16* sr_[6]; const u16* sc_[6];
    for (int i = 0; i < 6; ++i){
        pr_[i] = canp[16+i]; cr_[i] = canp[22+i];
        sr_[i] = canp[28+i]; sc_[i] = canp[34+i];
    }

    kc_all  <<<1425,256, 0, stream>>>(t, d_in[0], d_in[1], d_in[14], d_in[12],
                 d_in[5], d_in[7], can, scal, wcat, wembT, bex);
    k1_embed<<<1024,256, 0, stream>>>(canp[0], canp[1], canp[2], s1);
    k2_adj  <<<1,   256, 0, stream>>>(canp[3], canp[4], canp[2],
                 pr_[0],pr_[1],pr_[2],pr_[3],pr_[4],pr_[5], s1, scal, adjb, beff);
    k2b_mfma<<<64,  256, 0, stream>>>(adjb, wembT, weff);
    kvw     <<<260, 256, 0, stream>>>(canp[5], weff, beff, vw, vbias);
    k3_stats<<<1024,256, 0, stream>>>(canp[0], weff, beff, vw, vbias, s2);
    k3b_ctrl<<<1,   256, 0, stream>>>(canp[6], canp[5], canp[9], canp[11], canp[10],
                 cr_[0],cr_[1],cr_[2],cr_[3],cr_[4],cr_[5], s2, scal, bex);
    kbw     <<<312, 256, 0, stream>>>(bex, weff, beff, canp[8], wc, sw, bc, sb);
    k4_stats<<<1024,256, 0, stream>>>(canp[0], wc, sw, bc, sb, scal, wpack, s3);
    k5ab    <<<64,  256, 0, stream>>>(s3, canp[10],
                 sr_[0],sr_[1],sr_[2],sr_[3],sr_[4],sr_[5], scal, d_out);
    k6_read <<<512, 128, 0, stream>>>(canp[0], wpack, wc, bc, wcat, canp[10], canp[15],
                 scal, d_out, hbuf, s4);
    k8_proj <<<128, 256, 0, stream>>>(hbuf, canp[13],
                 sc_[0],sc_[1],sc_[2],sc_[3],sc_[4],sc_[5], s4, scal, d_out);
}